// Round 9
// baseline (1127.919 us; speedup 1.0000x reference)
//
#include <hip/hip_runtime.h>
#include <hip/hip_cooperative_groups.h>
#include <math.h>
#include <stdint.h>

namespace cg = cooperative_groups;

// ArcFace loss via MX-fp8 (e4m3, identity scales) MFMA GEMM + fused
// fixed-max softmax. B=2048, D=512, C=50000. Output: scalar mean NLL (f32).
//
// R14: ONE cooperative mega-kernel (prep -> grid.sync -> gemm -> grid.sync ->
//      fin -> grid.sync -> final reduce). R13's ledger: 165us of dispatches +
//      ~68us of inter-dispatch gaps; gaps die with the launches. 896
//      persistent blocks (2 gemm units each, zero imbalance; (bid+896)&7 ==
//      bid&7 keeps XCD chunk affinity). Gemm unit = R13 counted-vmcnt scheme
//      on a 2x16KB buffer pair (WAR barrier before re-stage). cg syncs need
//      no ws state -> nothing to pre-zero against the harness poison fill.
//      Host falls back to the R13 3-launch path if cooperative launch errors.
//
// Numerics: logits = 30*cos in [-30,30] -> fixed max 30, plain sums:
//   lse = 30 + log(sum_c exp(l_c - 30)); label logit recomputed exactly in
//   fp32 at finalize, so fp8 error only perturbs the softmax denominator.

#define B_ROWS    2048
#define D_DIM     512
#define C_CLASSES 50000
#define C_PAD     50176            // 112 * 448
#define NCHUNK    112              // 448-wide chunks
#define CH_COLS   448
#define NSTRIP    14               // 32-col strips per chunk
#define NUNITS_GEMM 1792           // 16 row-blocks x 112 chunks
#define NUNITS_PREP 6528           // 52224 rows / 8
#define GRID_MEGA 896
#define ARC_MARGIN 0.3f
#define ARC_SCALE  30.0f
#define ARC_EPS    1e-12f
#define K_LOG2E_S  43.2808512f     // 30 * log2(e)

// workspace layout (bytes)
#define OFF_WQ    0u               // 50176*512 = 25,690,112
#define OFF_EMBQ  25690112u        // 2048*512  =  1,048,576
#define OFF_WINV  26738688u        // 50000*4   =    200,000
#define OFF_EINV  26938688u        // 2048*4    =      8,192
#define OFF_PART  26946880u        // 2048*112*4 =   917,504
#define OFF_FINP  27864384u        // 256*4     =      1,024
#define OFF_TICK  27865408u        // 4 (fallback path only)   -> ~27.9 MB

typedef __attribute__((ext_vector_type(8))) int   i32x8;
typedef __attribute__((ext_vector_type(4))) int   i32x4;
typedef __attribute__((ext_vector_type(4))) float f32x4;

typedef __attribute__((address_space(1))) const unsigned int g_u32;
typedef __attribute__((address_space(3))) unsigned int       l_u32;

__device__ __forceinline__ void gload_lds16(const void* g, void* l) {
    // dest is wave-uniform LDS base; HW writes lane i at base + i*16
    g_u32* gp = (g_u32*)(uintptr_t)g;
    l_u32* lp = (l_u32*)(uintptr_t)l;
    __builtin_amdgcn_global_load_lds(gp, lp, 16, 0, 0);
}

// ---------------- prep unit: 8 consecutive rows -> e4m3 + inverse norms ------
// All 16 row-loads issued before use (256 B/lane outstanding). Segments
// (50000 weight / 176 pad / 2048 emb) are all multiples of 8 rows.
__device__ __forceinline__ void prep_unit(int g0, int lane,
                                          const float* __restrict__ emb,
                                          const float* __restrict__ weight,
                                          uint8_t* __restrict__ embq,
                                          uint8_t* __restrict__ wq,
                                          float* __restrict__ einv,
                                          float* __restrict__ winv) {
    const float* src;
    uint8_t* dst;
    float* invout;
    if (g0 >= C_PAD) {                 // embedding rows
        int row = g0 - C_PAD;
        src = emb + (size_t)row * D_DIM;
        dst = embq + (size_t)row * D_DIM;
        invout = einv + row;
    } else if (g0 >= C_CLASSES) {      // zero-fill pad classes
        int2 z = make_int2(0, 0);
        #pragma unroll
        for (int r = 0; r < 8; ++r)
            *(int2*)(wq + (size_t)(g0 + r) * D_DIM + lane * 8) = z;
        return;
    } else {                           // weight rows
        src = weight + (size_t)g0 * D_DIM;
        dst = wq + (size_t)g0 * D_DIM;
        invout = winv + g0;
    }

    const float4* r4 = (const float4*)src;
    float4 v[16];
    #pragma unroll
    for (int r = 0; r < 8; ++r) {
        v[2 * r]     = r4[r * 128 + lane * 2];
        v[2 * r + 1] = r4[r * 128 + lane * 2 + 1];
    }

    #pragma unroll
    for (int r = 0; r < 8; ++r) {
        float4 v0 = v[2 * r], v1 = v[2 * r + 1];
        float s = v0.x*v0.x + v0.y*v0.y + v0.z*v0.z + v0.w*v0.w
                + v1.x*v1.x + v1.y*v1.y + v1.z*v1.z + v1.w*v1.w;
        #pragma unroll
        for (int off = 32; off; off >>= 1) s += __shfl_xor(s, off);
        float rn = 1.0f / fmaxf(sqrtf(s), ARC_EPS);
        if (lane == 0) invout[r] = rn;
        int p0 = __builtin_amdgcn_cvt_pk_fp8_f32(v0.x * rn, v0.y * rn, 0, false);
        p0     = __builtin_amdgcn_cvt_pk_fp8_f32(v0.z * rn, v0.w * rn, p0, true);
        int p1 = __builtin_amdgcn_cvt_pk_fp8_f32(v1.x * rn, v1.y * rn, 0, false);
        p1     = __builtin_amdgcn_cvt_pk_fp8_f32(v1.z * rn, v1.w * rn, p1, true);
        *(int2*)(dst + (size_t)r * D_DIM + lane * 8) = make_int2(p0, p1);
    }
}

// ---------------- gemm unit: 128 rows x 448 cols, fused exp-sum --------------
// 4 waves x 32 rows; A full-K in regs; B strips (32 cols, 16KB) in 2-buffer
// LDS with counted vmcnt: stage-ahead issued after a WAR barrier, vmcnt(4)
// gate keeps one strip permanently in flight (A-frag loads are OLDER in the
// wave's FIFO so vmcnt(4) also covers them). Same validated math as R13.
template <bool MASK>
__device__ __forceinline__ void gemm_unit(int id, int w, int lane, int c, int q,
                                          const uint8_t* __restrict__ embq,
                                          const uint8_t* __restrict__ wq,
                                          float* __restrict__ partials,
                                          uint8_t (&Bs)[2][16384]) {
    const int xcd = id & 7;
    const int s   = id >> 3;
    const int ci  = s % 14;
    const int rb  = s / 14;
    const int chunk = xcd * 14 + ci;
    const int b0 = rb * 128;
    const int n0 = chunk * CH_COLS;

    // ---- A fragments: wave's 32 rows, full K=512, in registers ----
    const int r0 = b0 + w * 32;
    i32x8 afA[4], afB[4];
    #pragma unroll
    for (int kt = 0; kt < 4; ++kt) {
        const uint8_t* pa = embq + (size_t)(r0 + c) * D_DIM + kt * 128 + q * 32;
        const uint8_t* pb = embq + (size_t)(r0 + 16 + c) * D_DIM + kt * 128 + q * 32;
        i32x4 alo = *(const i32x4*)pa;
        i32x4 ahi = *(const i32x4*)(pa + 16);
        i32x4 blo = *(const i32x4*)pb;
        i32x4 bhi = *(const i32x4*)(pb + 16);
        afA[kt] = (i32x8){alo[0], alo[1], alo[2], alo[3], ahi[0], ahi[1], ahi[2], ahi[3]};
        afB[kt] = (i32x8){blo[0], blo[1], blo[2], blo[3], bhi[0], bhi[1], bhi[2], bhi[3]};
    }

    auto stage = [&](uint8_t* dst, int st) {
        const uint8_t* base_ = wq + (size_t)(n0 + st * 32) * D_DIM;
        #pragma unroll
        for (int t = 0; t < 4; ++t) {
            const int p  = w * 4 + t;          // 0..15
            const int cb = p >> 3;             // 0..1 : 16-col group
            const int h  = p & 7;              // 0..7 : kc block of 4
            gload_lds16(base_ + (size_t)(cb * 16 + c) * D_DIM + (h * 4 + q) * 16,
                        dst + cb * 8192 + h * 1024);
        }
    };

    f32x4 rs0 = (f32x4){0.f, 0.f, 0.f, 0.f};
    f32x4 rs1 = (f32x4){0.f, 0.f, 0.f, 0.f};

    auto compute = [&](const uint8_t* buf, int st) {
        #pragma unroll
        for (int cb = 0; cb < 2; ++cb) {
            f32x4 a0 = (f32x4){0.f, 0.f, 0.f, 0.f};
            f32x4 a1 = (f32x4){0.f, 0.f, 0.f, 0.f};
            #pragma unroll
            for (int kt = 0; kt < 4; ++kt) {
                const uint8_t* p = buf + cb * 8192 + (kt * 8 + 2 * q) * 256 + c * 16;
                i32x4 lo = *(const i32x4*)p;
                i32x4 hi = *(const i32x4*)(p + 256);
                i32x8 bf = (i32x8){lo[0], lo[1], lo[2], lo[3],
                                   hi[0], hi[1], hi[2], hi[3]};
                a0 = __builtin_amdgcn_mfma_scale_f32_16x16x128_f8f6f4(
                        afA[kt], bf, a0, 0, 0, 0, 127, 0, 127);
                a1 = __builtin_amdgcn_mfma_scale_f32_16x16x128_f8f6f4(
                        afB[kt], bf, a1, 0, 0, 0, 127, 0, 127);
            }
            bool pad = false;
            if (MASK) pad = (n0 + st * 32 + cb * 16 + c) >= C_CLASSES;
            #pragma unroll
            for (int reg = 0; reg < 4; ++reg) {
                float t0 = __builtin_amdgcn_exp2f(fmaf(a0[reg], K_LOG2E_S, -K_LOG2E_S));
                float t1 = __builtin_amdgcn_exp2f(fmaf(a1[reg], K_LOG2E_S, -K_LOG2E_S));
                if (MASK && pad) { t0 = 0.f; t1 = 0.f; }
                rs0[reg] += t0;
                rs1[reg] += t1;
            }
        }
    };

    __syncthreads();                    // WAR: prior unit's readers done with Bs
    stage(&Bs[0][0], 0);
    stage(&Bs[1][0], 1);
    #pragma unroll 1
    for (int st = 0; st < NSTRIP; ++st) {
        if (st < NSTRIP - 1) asm volatile("s_waitcnt vmcnt(4)" ::: "memory");
        else                 asm volatile("s_waitcnt vmcnt(0)" ::: "memory");
        __builtin_amdgcn_s_barrier();       // strip st resident for all waves
        __builtin_amdgcn_sched_barrier(0);
        compute(&Bs[st & 1][0], st);
        if (st + 2 < NSTRIP) {
            __builtin_amdgcn_s_barrier();   // WAR: all waves done reading st
            stage(&Bs[st & 1][0], st + 2);  // its loads fly under compute(st+1)
        }
    }

    // wave-level col reduction: sum rs over the 16 col-lanes
    #pragma unroll
    for (int off = 1; off < 16; off <<= 1) {
        #pragma unroll
        for (int reg = 0; reg < 4; ++reg) {
            rs0[reg] += __shfl_xor(rs0[reg], off);
            rs1[reg] += __shfl_xor(rs1[reg], off);
        }
    }
    if (c == 0) {                               // lanes 0,16,32,48
        #pragma unroll
        for (int reg = 0; reg < 4; ++reg) {
            partials[(size_t)(r0 + q * 4 + reg) * NCHUNK + chunk]      = rs0[reg];
            partials[(size_t)(r0 + 16 + q * 4 + reg) * NCHUNK + chunk] = rs1[reg];
        }
    }
}

// ---------------- fin core: 8 rows -> finpart[fb] ----------------------------
__device__ __forceinline__ void fin_core(int fb, int w, int lane,
                                         const float* __restrict__ emb,
                                         const float* __restrict__ weight,
                                         const float* __restrict__ einv,
                                         const float* __restrict__ winv,
                                         const int* __restrict__ labels,
                                         const float* __restrict__ partials,
                                         float* __restrict__ finpart,
                                         float* sm8) {
    int b0 = fb * 8 + w * 2;
    int lab[2] = {labels[b0], labels[b0 + 1]};
    float4 e0[2], e1[2], w0[2], w1[2];
    float p0[2], p1[2];
    #pragma unroll
    for (int r = 0; r < 2; ++r) {
        const float4* e  = (const float4*)(emb + (size_t)(b0 + r) * D_DIM);
        const float4* wt = (const float4*)(weight + (size_t)lab[r] * D_DIM);
        e0[r] = e[lane];  e1[r] = e[lane + 64];
        w0[r] = wt[lane]; w1[r] = wt[lane + 64];
        p0[r] = partials[(size_t)(b0 + r) * NCHUNK + lane];
        p1[r] = (lane + 64 < NCHUNK)
              ? partials[(size_t)(b0 + r) * NCHUNK + lane + 64] : 0.f;
    }
    #pragma unroll
    for (int r = 0; r < 2; ++r) {
        float dot = e0[r].x*w0[r].x + e0[r].y*w0[r].y + e0[r].z*w0[r].z + e0[r].w*w0[r].w
                  + e1[r].x*w1[r].x + e1[r].y*w1[r].y + e1[r].z*w1[r].z + e1[r].w*w1[r].w;
        float ls = p0[r] + p1[r];
        #pragma unroll
        for (int off = 32; off; off >>= 1) {
            dot += __shfl_xor(dot, off);
            ls  += __shfl_xor(ls, off);
        }
        if (lane == 0) {
            int b = b0 + r;
            float cosv   = dot * einv[b] * winv[lab[r]];
            float l_orig = ARC_SCALE * cosv;
            float l_adj  = ARC_SCALE * (cosv - ARC_MARGIN);
            // swap (fp8-accumulated) label term for exact margin-adjusted one
            float s_adj = ls - __expf(l_orig - ARC_SCALE) + __expf(l_adj - ARC_SCALE);
            sm8[w * 2 + r] = ARC_SCALE + logf(s_adj) - l_adj;
        }
    }
    __syncthreads();
    if (w == 0 && lane == 0) {
        float t = 0.f;
        #pragma unroll
        for (int i = 0; i < 8; ++i) t += sm8[i];
        finpart[fb] = t;
    }
}

// ======================= cooperative mega-kernel =============================
__global__ __launch_bounds__(256, 4) void k_mega(
        const float* __restrict__ emb, const int* __restrict__ labels,
        const float* __restrict__ weight, uint8_t* __restrict__ embq,
        uint8_t* __restrict__ wq, float* __restrict__ einv,
        float* __restrict__ winv, float* __restrict__ partials,
        float* __restrict__ finpart, float* __restrict__ out) {
    __shared__ __align__(16) uint8_t Bs[2][16384];
    __shared__ float sm8[8];
    const int tid = threadIdx.x;
    const int w = tid >> 6, lane = tid & 63;
    const int c = lane & 15, q = lane >> 4;
    cg::grid_group grid = cg::this_grid();

    // ---- phase 1: prep (6528 units over 3584 waves) ----
    #pragma unroll 1
    for (int u = blockIdx.x * 4 + w; u < NUNITS_PREP; u += GRID_MEGA * 4)
        prep_unit(u << 3, lane, emb, weight, embq, wq, einv, winv);
    __threadfence();
    grid.sync();

    // ---- phase 2: gemm (2 units per block, XCD affinity: (bid+896)&7==bid&7)
    #pragma unroll 1
    for (int unit = blockIdx.x; unit < NUNITS_GEMM; unit += GRID_MEGA) {
        const int chunk = (unit & 7) * 14 + ((unit >> 3) % 14);
        if (chunk == NCHUNK - 1)
            gemm_unit<true>(unit, w, lane, c, q, embq, wq, partials, Bs);
        else
            gemm_unit<false>(unit, w, lane, c, q, embq, wq, partials, Bs);
    }
    __threadfence();
    grid.sync();

    // ---- phase 3: fin (blocks 0..255) + final reduce (block 0) ----
    if (blockIdx.x < 256)
        fin_core(blockIdx.x, w, lane, emb, weight, einv, winv, labels,
                 partials, finpart, sm8);
    __threadfence();
    grid.sync();
    if (blockIdx.x == 0) {
        float v = finpart[tid];
        #pragma unroll
        for (int off = 32; off; off >>= 1) v += __shfl_xor(v, off);
        if (lane == 0) sm8[w] = v;
        __syncthreads();
        if (tid == 0)
            out[0] = (sm8[0] + sm8[1] + sm8[2] + sm8[3]) * (1.0f / (float)B_ROWS);
    }
}

// ======================= fallback path (R13 three-launch) ====================
__global__ __launch_bounds__(256) void k_prep_fb(const float* __restrict__ emb,
                                                 const float* __restrict__ weight,
                                                 uint8_t* __restrict__ embq,
                                                 uint8_t* __restrict__ wq,
                                                 float* __restrict__ einv,
                                                 float* __restrict__ winv,
                                                 unsigned int* __restrict__ ticket) {
    if (blockIdx.x == 0 && threadIdx.x == 0) *ticket = 0u;
    int wave = blockIdx.x * 4 + (threadIdx.x >> 6);
    prep_unit(wave << 3, threadIdx.x & 63, emb, weight, embq, wq, einv, winv);
}

__global__ __launch_bounds__(256) void k_gemm_fb(const uint8_t* __restrict__ embq,
                                                 const uint8_t* __restrict__ wq,
                                                 float* __restrict__ partials) {
    __shared__ __align__(16) uint8_t Bs[2][16384];
    const int tid = threadIdx.x;
    const int w = tid >> 6, lane = tid & 63;
    const int c = lane & 15, q = lane >> 4;
    const int id = blockIdx.x;
    const int chunk = (id & 7) * 14 + ((id >> 3) % 14);
    if (chunk == NCHUNK - 1)
        gemm_unit<true>(id, w, lane, c, q, embq, wq, partials, Bs);
    else
        gemm_unit<false>(id, w, lane, c, q, embq, wq, partials, Bs);
}

__global__ __launch_bounds__(256) void k_fin_fb(const float* __restrict__ emb,
                                                const float* __restrict__ weight,
                                                const float* __restrict__ einv,
                                                const float* __restrict__ winv,
                                                const int* __restrict__ labels,
                                                const float* __restrict__ partials,
                                                float* __restrict__ finpart,
                                                unsigned int* __restrict__ ticket,
                                                float* __restrict__ out) {
    __shared__ float sm8[8];
    __shared__ int is_last;
    const int tid = threadIdx.x;
    const int w = tid >> 6, lane = tid & 63;
    fin_core(blockIdx.x, w, lane, emb, weight, einv, winv, labels,
             partials, finpart, sm8);
    if (tid == 0) {
        __threadfence();
        unsigned int old = atomicAdd(ticket, 1u);
        is_last = (old == gridDim.x - 1) ? 1 : 0;
    }
    __syncthreads();
    if (is_last) {
        __threadfence();
        volatile const float* fp = finpart;
        float v = fp[tid];
        #pragma unroll
        for (int off = 32; off; off >>= 1) v += __shfl_xor(v, off);
        if (lane == 0) sm8[w] = v;
        __syncthreads();
        if (tid == 0)
            out[0] = (sm8[0] + sm8[1] + sm8[2] + sm8[3]) * (1.0f / (float)B_ROWS);
    }
}

extern "C" void kernel_launch(void* const* d_in, const int* in_sizes, int n_in,
                              void* d_out, int out_size, void* d_ws, size_t ws_size,
                              hipStream_t stream) {
    const float* emb    = (const float*)d_in[0];   // (2048, 512) f32
    const int*   labels = (const int*)d_in[1];     // (2048,)
    const float* weight = (const float*)d_in[2];   // (50000, 512) f32
    float* out = (float*)d_out;

    char* ws = (char*)d_ws;
    uint8_t* wq    = (uint8_t*)(ws + OFF_WQ);
    uint8_t* embq  = (uint8_t*)(ws + OFF_EMBQ);
    float* winv     = (float*)(ws + OFF_WINV);
    float* einv     = (float*)(ws + OFF_EINV);
    float* partials = (float*)(ws + OFF_PART);
    float* finpart  = (float*)(ws + OFF_FINP);
    unsigned int* ticket = (unsigned int*)(ws + OFF_TICK);

    void* args[] = {(void*)&emb, (void*)&labels, (void*)&weight, (void*)&embq,
                    (void*)&wq, (void*)&einv, (void*)&winv, (void*)&partials,
                    (void*)&finpart, (void*)&out};
    hipError_t err = hipLaunchCooperativeKernel((void*)k_mega, dim3(GRID_MEGA),
                                                dim3(256), args, 0, stream);
    if (err != hipSuccess) {
        (void)hipGetLastError();   // clear sticky error; run classic path
        k_prep_fb<<<(C_PAD + B_ROWS) / 32, 256, 0, stream>>>(emb, weight, embq,
                                                             wq, einv, winv,
                                                             ticket);
        k_gemm_fb<<<NUNITS_GEMM, 256, 0, stream>>>(embq, wq, partials);
        k_fin_fb<<<B_ROWS / 8, 256, 0, stream>>>(emb, weight, einv, winv,
                                                 labels, partials, finpart,
                                                 ticket, out);
    }
}